// Round 8
// baseline (528.082 us; speedup 1.0000x reference)
//
#include <hip/hip_runtime.h>

// GraphAttentionLayer: x(8192,512) f32, support(8192,8192) i32{0,1},
// W(512,256) f32, a(512,1) f32  ->  out(8192,256) f32
//
// Decomposition (softmax shift cancels in numerator/denominator):
//   h = x@W (bf16 MFMA); s = h@a1, t = h@a2
//   top rows i<4096 : out = elu((eL*TL + eR*TR)/(eL*DL + eR*DR))
//   bot rows i>=4096: out = elu(TB/DB),  TB = sup@[wb.*h], DB = sup@wb
//
// k_mgemm v8 (strip-down): NO LDS, NO barriers, NO manual vmcnt. Each wave
// independently owns 32 rows x 256 cols x K=1024. A(support) feeds MFMA
// fragments via a depth-4 statically-named register pipeline (no rotation,
// no arrays -> no spill, no same-iter dependency). B fragments stream from
// the XCD-pinned L2-resident window each step. Denominator computed in VALU
// from the same A bits (w = ones for top / wb for bottom) -> N=256 exactly,
// acc = 128 VGPR. Partials P[8]/D[8] per K-window q, combined in k_out.

typedef short bf16x8 __attribute__((ext_vector_type(8)));
typedef float f32x4 __attribute__((ext_vector_type(4)));

static __device__ __forceinline__ unsigned short f2bf(float f) {
    unsigned int u = __builtin_bit_cast(unsigned int, f);
    unsigned int r = (u + 0x7FFFu + ((u >> 16) & 1u)) >> 16;
    return (unsigned short)r;
}
static __device__ __forceinline__ float bf2f(unsigned short s) {
    unsigned int u = ((unsigned int)s) << 16;
    return __builtin_bit_cast(float, u);
}

// ---- k1a: x f32 -> bf16 row-major [8192][512]
__global__ __launch_bounds__(256) void k_cvt_x(const float* __restrict__ x,
                                               unsigned short* __restrict__ xb) {
    int i = (blockIdx.x * 256 + threadIdx.x) * 4;
    float4 v = *(const float4*)(x + i);
    ushort4 o = make_ushort4(f2bf(v.x), f2bf(v.y), f2bf(v.z), f2bf(v.w));
    *(ushort4*)(xb + i) = o;
}

// ---- k1b: W [512][256] f32 -> Wbt [256][512] bf16 (n-major, k-contiguous)
__global__ __launch_bounds__(256) void k_cvt_w(const float* __restrict__ W,
                                               unsigned short* __restrict__ Wbt) {
    int idx = blockIdx.x * 256 + threadIdx.x;
    int n = idx >> 9, k = idx & 511;
    Wbt[idx] = f2bf(W[k * 256 + n]);
}

// ---- k2: h = xb @ Wbt^T. Writes h row-major bf16 AND B1t [256][8192] (h^T).
__global__ __launch_bounds__(256) void k_gemm_h(const unsigned short* __restrict__ xb,
                                                const unsigned short* __restrict__ Wbt,
                                                unsigned short* __restrict__ h,
                                                unsigned short* __restrict__ B1t) {
    __shared__ unsigned short Asm[128][72];
    __shared__ unsigned short Bsm[64][72];
    int tid = threadIdx.x;
    int wv = tid >> 6, ln = tid & 63;
    int m0 = blockIdx.x * 128, n0 = blockIdx.y * 64;

    f32x4 acc[2][4];
#pragma unroll
    for (int i = 0; i < 2; i++)
#pragma unroll
        for (int j = 0; j < 4; j++) acc[i][j] = (f32x4)0.0f;

    for (int k0 = 0; k0 < 512; k0 += 64) {
        {
            int r = tid >> 1, c = (tid & 1) * 32;
            const unsigned short* src = xb + (m0 + r) * 512 + k0 + c;
            *(bf16x8*)&Asm[r][c]      = *(const bf16x8*)(src);
            *(bf16x8*)&Asm[r][c + 8]  = *(const bf16x8*)(src + 8);
            *(bf16x8*)&Asm[r][c + 16] = *(const bf16x8*)(src + 16);
            *(bf16x8*)&Asm[r][c + 24] = *(const bf16x8*)(src + 24);
        }
        {
            int r = tid >> 2, c = (tid & 3) * 16;
            const unsigned short* src = Wbt + (n0 + r) * 512 + k0 + c;
            *(bf16x8*)&Bsm[r][c]     = *(const bf16x8*)(src);
            *(bf16x8*)&Bsm[r][c + 8] = *(const bf16x8*)(src + 8);
        }
        __syncthreads();
        int lr = ln & 15, lk = (ln >> 4) * 8;
#pragma unroll
        for (int ks = 0; ks < 2; ks++) {
            int kk = ks * 32 + lk;
            bf16x8 a0 = *(const bf16x8*)&Asm[wv * 32 + lr][kk];
            bf16x8 a1 = *(const bf16x8*)&Asm[wv * 32 + 16 + lr][kk];
#pragma unroll
            for (int nt = 0; nt < 4; nt++) {
                bf16x8 b = *(const bf16x8*)&Bsm[nt * 16 + lr][kk];
                acc[0][nt] = __builtin_amdgcn_mfma_f32_16x16x32_bf16(a0, b, acc[0][nt], 0, 0, 0);
                acc[1][nt] = __builtin_amdgcn_mfma_f32_16x16x32_bf16(a1, b, acc[1][nt], 0, 0, 0);
            }
        }
        __syncthreads();
    }
    int lr = ln & 15, lrow = (ln >> 4) * 4;
#pragma unroll
    for (int mt = 0; mt < 2; mt++) {
#pragma unroll
        for (int nt = 0; nt < 4; nt++) {
            int mg = m0 + wv * 32 + mt * 16 + lrow;
            int ng = n0 + nt * 16 + lr;
            ushort4 tb = make_ushort4(f2bf(acc[mt][nt][0]), f2bf(acc[mt][nt][1]),
                                      f2bf(acc[mt][nt][2]), f2bf(acc[mt][nt][3]));
            h[(mg + 0) * 256 + ng] = tb.x;
            h[(mg + 1) * 256 + ng] = tb.y;
            h[(mg + 2) * 256 + ng] = tb.z;
            h[(mg + 3) * 256 + ng] = tb.w;
            *(ushort4*)&B1t[ng * 8192 + mg] = tb;
        }
    }
}

// ---- k3: s[j], t[j]
__global__ __launch_bounds__(256) void k_st(const unsigned short* __restrict__ h,
                                            const float* __restrict__ a,
                                            float* __restrict__ s, float* __restrict__ t) {
    int wv = threadIdx.x >> 6, ln = threadIdx.x & 63;
    int j = blockIdx.x * 4 + wv;
    ushort4 hv = *(const ushort4*)(h + j * 256 + ln * 4);
    float4 a1 = *(const float4*)(a + ln * 4);
    float4 a2 = *(const float4*)(a + 256 + ln * 4);
    float s_ = bf2f(hv.x) * a1.x + bf2f(hv.y) * a1.y + bf2f(hv.z) * a1.z + bf2f(hv.w) * a1.w;
    float t_ = bf2f(hv.x) * a2.x + bf2f(hv.y) * a2.y + bf2f(hv.z) * a2.z + bf2f(hv.w) * a2.w;
#pragma unroll
    for (int off = 32; off; off >>= 1) {
        s_ += __shfl_down(s_, off);
        t_ += __shfl_down(t_, off);
    }
    if (ln == 0) { s[j] = s_; t[j] = t_; }
}

// ---- k3b: wb / eL / eR / ones
__global__ __launch_bounds__(256) void k_weights(const float* __restrict__ s,
                                                 const float* __restrict__ t,
                                                 float* __restrict__ wb,
                                                 float* __restrict__ eL,
                                                 float* __restrict__ eR,
                                                 float* __restrict__ ones) {
    int j = blockIdx.x * 256 + threadIdx.x;
    float eb = s[(2 * j) & 8191] + t[(2 * j + 1) & 8191];
    eb = eb > 0.0f ? eb : 0.2f * eb;
    wb[j] = expf(eb);
    ones[j] = 1.0f;
    if (j < 4096) {
        float cL = s[2 * j] + t[2 * j];
        cL = cL > 0.0f ? cL : 0.2f * cL;
        float cR = s[2 * j + 1] + t[2 * j + 1];
        cR = cR > 0.0f ? cR : 0.2f * cR;
        eL[j] = expf(cL);
        eR[j] = expf(cR);
    }
}

// ---- k4: B2t[f][j] = wb[j] * B1t[f][j]   (f < 256)
__global__ __launch_bounds__(256) void k_b2(const unsigned short* __restrict__ B1t,
                                            const float* __restrict__ wb,
                                            unsigned short* __restrict__ B2t) {
    int j = blockIdx.x * 256 + threadIdx.x;
    int f = blockIdx.y;
    B2t[f * 8192 + j] = f2bf(wb[j] * bf2f(B1t[f * 8192 + j]));
}

// ---- k5: masked GEMM v8 (see header comment).
static __device__ __forceinline__ bf16x8 cvt01(int4 a, int4 b) {
    bf16x8 r;
    r[0] = a.x ? (short)0x3F80 : (short)0; r[1] = a.y ? (short)0x3F80 : (short)0;
    r[2] = a.z ? (short)0x3F80 : (short)0; r[3] = a.w ? (short)0x3F80 : (short)0;
    r[4] = b.x ? (short)0x3F80 : (short)0; r[5] = b.y ? (short)0x3F80 : (short)0;
    r[6] = b.z ? (short)0x3F80 : (short)0; r[7] = b.w ? (short)0x3F80 : (short)0;
    return r;
}

static __device__ __forceinline__ void step_mfma(
        int4 s0, int4 s1, int4 s2, int4 s3, int it,
        const unsigned short* __restrict__ bp, const float* __restrict__ wp,
        f32x4* __restrict__ acc0, f32x4* __restrict__ acc1,
        float& den0, float& den1) {
    float4 w0 = *(const float4*)(wp + it * 32);
    float4 w1 = *(const float4*)(wp + it * 32 + 4);
    den0 += (s0.x ? w0.x : 0.0f) + (s0.y ? w0.y : 0.0f)
          + (s0.z ? w0.z : 0.0f) + (s0.w ? w0.w : 0.0f)
          + (s1.x ? w1.x : 0.0f) + (s1.y ? w1.y : 0.0f)
          + (s1.z ? w1.z : 0.0f) + (s1.w ? w1.w : 0.0f);
    den1 += (s2.x ? w0.x : 0.0f) + (s2.y ? w0.y : 0.0f)
          + (s2.z ? w0.z : 0.0f) + (s2.w ? w0.w : 0.0f)
          + (s3.x ? w1.x : 0.0f) + (s3.y ? w1.y : 0.0f)
          + (s3.z ? w1.z : 0.0f) + (s3.w ? w1.w : 0.0f);
    bf16x8 av0 = cvt01(s0, s1);
    bf16x8 av1 = cvt01(s2, s3);
#pragma unroll
    for (int f = 0; f < 16; f++) {
        bf16x8 bv = *(const bf16x8*)(bp + (long)f * 131072 + it * 32);
        acc0[f] = __builtin_amdgcn_mfma_f32_16x16x32_bf16(av0, bv, acc0[f], 0, 0, 0);
        acc1[f] = __builtin_amdgcn_mfma_f32_16x16x32_bf16(av1, bv, acc1[f], 0, 0, 0);
    }
}

__global__ __launch_bounds__(256, 2) void k_mgemm(const int* __restrict__ sup,
                                                  const unsigned short* __restrict__ B1t,
                                                  const unsigned short* __restrict__ B2t,
                                                  const float* __restrict__ ones,
                                                  const float* __restrict__ wb,
                                                  float* __restrict__ P,
                                                  float* __restrict__ D) {
    int tid = threadIdx.x, wv = tid >> 6, ln = tid & 63;
    int bid = blockIdx.x;
    int q = bid & 7;                 // XCD-pinned K-window
    int strip = bid >> 3;            // 0..63
    long K0 = (long)q * 1024;
    long m0 = (long)strip * 128;
    bool topv = strip < 32;
    const unsigned short* Bt = topv ? B1t : B2t;
    const float* wsel = topv ? ones : wb;

    // per-lane fragment addressing: row = ln&15 (+16 for frag1), kchunk = (ln>>4)*8
    const int* ap0 = sup + (m0 + wv * 32 + (ln & 15)) * 8192 + K0 + (ln >> 4) * 8;
    const int* ap1 = ap0 + 16 * 8192;
    const unsigned short* bp = Bt + (long)(ln & 15) * 8192 + K0 + (ln >> 4) * 8;
    const float* wp = wsel + K0 + (ln >> 4) * 8;

    f32x4 acc0[16], acc1[16];
#pragma unroll
    for (int i = 0; i < 16; i++) { acc0[i] = (f32x4)0.0f; acc1[i] = (f32x4)0.0f; }
    float den0 = 0.0f, den1 = 0.0f;

    int4 sA0, sA1, sA2, sA3, sB0, sB1, sB2, sB3;
    int4 sC0, sC1, sC2, sC3, sD0, sD1, sD2, sD3;

#define LOAD_SLOT(S, T) do {                                          \
        const int* p0_ = ap0 + (long)(T) * 32;                        \
        const int* p1_ = ap1 + (long)(T) * 32;                        \
        S##0 = *(const int4*)(p0_); S##1 = *(const int4*)(p0_ + 4);   \
        S##2 = *(const int4*)(p1_); S##3 = *(const int4*)(p1_ + 4);   \
    } while (0)

    // depth-4 register pipeline, statically named slots, no barriers anywhere
    LOAD_SLOT(sA, 0); LOAD_SLOT(sB, 1); LOAD_SLOT(sC, 2); LOAD_SLOT(sD, 3);

#pragma unroll 1
    for (int it = 0; it < 28; it += 4) {
        step_mfma(sA0, sA1, sA2, sA3, it,     bp, wp, acc0, acc1, den0, den1);
        LOAD_SLOT(sA, it + 4);
        step_mfma(sB0, sB1, sB2, sB3, it + 1, bp, wp, acc0, acc1, den0, den1);
        LOAD_SLOT(sB, it + 5);
        step_mfma(sC0, sC1, sC2, sC3, it + 2, bp, wp, acc0, acc1, den0, den1);
        LOAD_SLOT(sC, it + 6);
        step_mfma(sD0, sD1, sD2, sD3, it + 3, bp, wp, acc0, acc1, den0, den1);
        LOAD_SLOT(sD, it + 7);
    }
    step_mfma(sA0, sA1, sA2, sA3, 28, bp, wp, acc0, acc1, den0, den1);
    step_mfma(sB0, sB1, sB2, sB3, 29, bp, wp, acc0, acc1, den0, den1);
    step_mfma(sC0, sC1, sC2, sC3, 30, bp, wp, acc0, acc1, den0, den1);
    step_mfma(sD0, sD1, sD2, sD3, 31, bp, wp, acc0, acc1, den0, den1);
#undef LOAD_SLOT

    // denominator: rows (ln&15) and (ln&15)+16; sum the 4 k-chunk lanes
    den0 += __shfl_xor(den0, 16); den0 += __shfl_xor(den0, 32);
    den1 += __shfl_xor(den1, 16); den1 += __shfl_xor(den1, 32);
    if (ln < 16) {
        D[(long)q * 8192 + m0 + wv * 32 + ln]      = den0;
        D[(long)q * 8192 + m0 + wv * 32 + 16 + ln] = den1;
    }

    // numerator partials: P[q][row][col], plain stores (no atomics)
    const long QS = 8192l * 256;
    long grow = m0 + wv * 32 + (ln >> 4) * 4;
    int lr = ln & 15;
    float* op = P + (long)q * QS + grow * 256 + lr;
#pragma unroll
    for (int f = 0; f < 16; f++) {
#pragma unroll
        for (int r = 0; r < 4; r++) {
            op[(long)r * 256 + f * 16]             = acc0[f][r];
            op[(long)(16 + r) * 256 + f * 16]      = acc1[f][r];
        }
    }
}

// ---- k6: combine 8 partials + elu
__global__ __launch_bounds__(256) void k_out(const float* __restrict__ P,
                                             const float* __restrict__ D,
                                             const float* __restrict__ eL,
                                             const float* __restrict__ eR,
                                             float* __restrict__ outp) {
    int i = blockIdx.x, f = threadIdx.x;
    const long QS = 8192l * 256;
    const float* p = P + (long)i * 256 + f;
    const float* d = D + i;
    float num, den;
    if (i < 4096) {
        float nl = 0, nr = 0, dl = 0, dr = 0;
#pragma unroll
        for (int q = 0; q < 4; q++) { nl += p[q * QS]; dl += d[q * 8192]; }
#pragma unroll
        for (int q = 4; q < 8; q++) { nr += p[q * QS]; dr += d[q * 8192]; }
        float el = eL[i], er = eR[i];
        num = el * nl + er * nr;
        den = el * dl + er * dr;
    } else {
        num = 0; den = 0;
#pragma unroll
        for (int q = 0; q < 8; q++) { num += p[q * QS]; den += d[q * 8192]; }
    }
    float r = num / den;
    outp[(long)i * 256 + f] = r > 0.0f ? r : expm1f(r);
}

extern "C" void kernel_launch(void* const* d_in, const int* in_sizes, int n_in,
                              void* d_out, int out_size, void* d_ws, size_t ws_size,
                              hipStream_t stream) {
    (void)in_sizes; (void)n_in; (void)out_size; (void)ws_size;
    const float* x = (const float*)d_in[0];
    const int* sup = (const int*)d_in[1];
    const float* W = (const float*)d_in[2];
    const float* a = (const float*)d_in[3];
    float* outp = (float*)d_out;

    char* ws = (char*)d_ws;
    size_t off = 0;
    auto alloc = [&](size_t bytes) -> void* {
        void* p = ws + off;
        off += (bytes + 255) & ~(size_t)255;
        return p;
    };
    unsigned short* xb   = (unsigned short*)alloc(8192 * 512 * 2);
    unsigned short* Wbt  = (unsigned short*)alloc(256 * 512 * 2);
    unsigned short* h    = (unsigned short*)alloc(8192 * 256 * 2);
    unsigned short* B1t  = (unsigned short*)alloc(256 * 8192 * 2);
    unsigned short* B2t  = (unsigned short*)alloc(256 * 8192 * 2);
    float* s    = (float*)alloc(8192 * 4);
    float* t    = (float*)alloc(8192 * 4);
    float* wb   = (float*)alloc(8192 * 4);
    float* eL   = (float*)alloc(4096 * 4);
    float* eR   = (float*)alloc(4096 * 4);
    float* ones = (float*)alloc(8192 * 4);
    float* P    = (float*)alloc((size_t)8 * 8192 * 256 * 4);   // 67 MB partials
    float* D    = (float*)alloc((size_t)8 * 8192 * 4);

    k_cvt_x<<<4096, 256, 0, stream>>>(x, xb);
    k_cvt_w<<<512, 256, 0, stream>>>(W, Wbt);
    k_gemm_h<<<dim3(64, 4), 256, 0, stream>>>(xb, Wbt, h, B1t);
    k_st<<<2048, 256, 0, stream>>>(h, a, s, t);
    k_weights<<<32, 256, 0, stream>>>(s, t, wb, eL, eR, ones);
    k_b2<<<dim3(32, 256), 256, 0, stream>>>(B1t, wb, B2t);
    k_mgemm<<<512, 256, 0, stream>>>(sup, B1t, B2t, ones, wb, P, D);
    k_out<<<8192, 256, 0, stream>>>(P, D, eL, eR, outp);
}

// Round 9
// 223.752 us; speedup vs baseline: 2.3601x; 2.3601x over previous
//
#include <hip/hip_runtime.h>

// GraphAttentionLayer: x(8192,512) f32, support(8192,8192) i32{0,1},
// W(512,256) f32, a(512,1) f32  ->  out(8192,256) f32
//
// Decomposition (softmax shift cancels in numerator/denominator):
//   h = x@W (bf16 MFMA); s = h@a1, t = h@a2
//   top rows i<4096 : out = elu((eL*TL + eR*TR)/(eL*TL[256] + eR*TR[256]))
//   bot rows i>=4096: out = elu(TB/TB[256]),  TB = sup[4096:, :] @ (wb .* [h|1])
//
// v9: k_pack streams support once (256 MB, ballot -> 8 MB bitmask; trivially
// HBM-saturating). k_mgemm then runs ENTIRELY from L2: A = 1 byte/lane/step
// from the bitmask (expanded to bf16 frags in VALU, co-issues with MFMA), B
// staged via global_load_lds 3 tiles ahead (4 LDS bufs) with counted
// vmcnt(14) + raw s_barrier (v6/v7 proven mechanics). Unroll-4 static slots
// (no rotation, no arrays) -> no spill. K-split q=0..7 XCD-pinned; partials
// P[8][8192][272] with plain stores; k_out combines.

typedef short bf16x8 __attribute__((ext_vector_type(8)));
typedef float f32x4 __attribute__((ext_vector_type(4)));

static __device__ __forceinline__ unsigned short f2bf(float f) {
    unsigned int u = __builtin_bit_cast(unsigned int, f);
    unsigned int r = (u + 0x7FFFu + ((u >> 16) & 1u)) >> 16;
    return (unsigned short)r;
}
static __device__ __forceinline__ float bf2f(unsigned short s) {
    unsigned int u = ((unsigned int)s) << 16;
    return __builtin_bit_cast(float, u);
}
static __device__ __forceinline__ void glds16(const unsigned short* g, unsigned short* l) {
    __builtin_amdgcn_global_load_lds(
        (const __attribute__((address_space(1))) unsigned int*)(g),
        (__attribute__((address_space(3))) unsigned int*)(l), 16, 0, 0);
}
// byte (8 bits of support) -> bf16x8 {0,1}: u32 w = (bit2w?1:0) | (bit2w+1?1:0)<<16
static __device__ __forceinline__ bf16x8 expand_byte(unsigned int b) {
    union { bf16x8 v; unsigned int u[4]; } r;
#pragma unroll
    for (int w = 0; w < 4; w++) {
        unsigned int lo = (b >> (2 * w)) & 1u;
        unsigned int hi = (b >> (2 * w + 1)) & 1u;
        r.u[w] = (lo ? 0x3F80u : 0u) | (hi ? 0x3F800000u : 0u);
    }
    return r.v;
}

// ---- k0: pack support -> bits[8192][1024] bytes (bit i of byte b = sup[r][8b+i])
__global__ __launch_bounds__(256) void k_pack(const int* __restrict__ sup,
                                              unsigned long long* __restrict__ bits) {
    int wid = (blockIdx.x << 2) | (threadIdx.x >> 6);   // row 0..8191
    int ln = threadIdx.x & 63;
    const int* rp = sup + (long)wid * 8192 + ln;
    unsigned long long* bp = bits + (long)wid * 128;
#pragma unroll 4
    for (int w = 0; w < 128; w++) {
        int v = rp[(long)w * 64];
        unsigned long long m = __ballot(v != 0);
        if (ln == 0) bp[w] = m;
    }
}

// ---- k1a: x f32 -> bf16 row-major [8192][512]
__global__ __launch_bounds__(256) void k_cvt_x(const float* __restrict__ x,
                                               unsigned short* __restrict__ xb) {
    int i = (blockIdx.x * 256 + threadIdx.x) * 4;
    float4 v = *(const float4*)(x + i);
    ushort4 o = make_ushort4(f2bf(v.x), f2bf(v.y), f2bf(v.z), f2bf(v.w));
    *(ushort4*)(xb + i) = o;
}

// ---- k1b: W [512][256] f32 -> Wbt [256][512] bf16
__global__ __launch_bounds__(256) void k_cvt_w(const float* __restrict__ W,
                                               unsigned short* __restrict__ Wbt) {
    int idx = blockIdx.x * 256 + threadIdx.x;
    int n = idx >> 9, k = idx & 511;
    Wbt[idx] = f2bf(W[k * 256 + n]);
}

// ---- k2: h = xb @ Wbt^T. Writes h row-major bf16 AND B1t [272][8192] rows 0..255.
__global__ __launch_bounds__(256) void k_gemm_h(const unsigned short* __restrict__ xb,
                                                const unsigned short* __restrict__ Wbt,
                                                unsigned short* __restrict__ h,
                                                unsigned short* __restrict__ B1t) {
    __shared__ unsigned short Asm[128][72];
    __shared__ unsigned short Bsm[64][72];
    int tid = threadIdx.x;
    int wv = tid >> 6, ln = tid & 63;
    int m0 = blockIdx.x * 128, n0 = blockIdx.y * 64;

    f32x4 acc[2][4];
#pragma unroll
    for (int i = 0; i < 2; i++)
#pragma unroll
        for (int j = 0; j < 4; j++) acc[i][j] = (f32x4)0.0f;

    for (int k0 = 0; k0 < 512; k0 += 64) {
        {
            int r = tid >> 1, c = (tid & 1) * 32;
            const unsigned short* src = xb + (m0 + r) * 512 + k0 + c;
            *(bf16x8*)&Asm[r][c]      = *(const bf16x8*)(src);
            *(bf16x8*)&Asm[r][c + 8]  = *(const bf16x8*)(src + 8);
            *(bf16x8*)&Asm[r][c + 16] = *(const bf16x8*)(src + 16);
            *(bf16x8*)&Asm[r][c + 24] = *(const bf16x8*)(src + 24);
        }
        {
            int r = tid >> 2, c = (tid & 3) * 16;
            const unsigned short* src = Wbt + (n0 + r) * 512 + k0 + c;
            *(bf16x8*)&Bsm[r][c]     = *(const bf16x8*)(src);
            *(bf16x8*)&Bsm[r][c + 8] = *(const bf16x8*)(src + 8);
        }
        __syncthreads();
        int lr = ln & 15, lk = (ln >> 4) * 8;
#pragma unroll
        for (int ks = 0; ks < 2; ks++) {
            int kk = ks * 32 + lk;
            bf16x8 a0 = *(const bf16x8*)&Asm[wv * 32 + lr][kk];
            bf16x8 a1 = *(const bf16x8*)&Asm[wv * 32 + 16 + lr][kk];
#pragma unroll
            for (int nt = 0; nt < 4; nt++) {
                bf16x8 b = *(const bf16x8*)&Bsm[nt * 16 + lr][kk];
                acc[0][nt] = __builtin_amdgcn_mfma_f32_16x16x32_bf16(a0, b, acc[0][nt], 0, 0, 0);
                acc[1][nt] = __builtin_amdgcn_mfma_f32_16x16x32_bf16(a1, b, acc[1][nt], 0, 0, 0);
            }
        }
        __syncthreads();
    }
    int lr = ln & 15, lrow = (ln >> 4) * 4;
#pragma unroll
    for (int mt = 0; mt < 2; mt++) {
#pragma unroll
        for (int nt = 0; nt < 4; nt++) {
            int mg = m0 + wv * 32 + mt * 16 + lrow;
            int ng = n0 + nt * 16 + lr;
            ushort4 tb = make_ushort4(f2bf(acc[mt][nt][0]), f2bf(acc[mt][nt][1]),
                                      f2bf(acc[mt][nt][2]), f2bf(acc[mt][nt][3]));
            h[(mg + 0) * 256 + ng] = tb.x;
            h[(mg + 1) * 256 + ng] = tb.y;
            h[(mg + 2) * 256 + ng] = tb.z;
            h[(mg + 3) * 256 + ng] = tb.w;
            *(ushort4*)&B1t[ng * 8192 + mg] = tb;
        }
    }
}

// ---- k3: s[j], t[j]
__global__ __launch_bounds__(256) void k_st(const unsigned short* __restrict__ h,
                                            const float* __restrict__ a,
                                            float* __restrict__ s, float* __restrict__ t) {
    int wv = threadIdx.x >> 6, ln = threadIdx.x & 63;
    int j = blockIdx.x * 4 + wv;
    ushort4 hv = *(const ushort4*)(h + j * 256 + ln * 4);
    float4 a1 = *(const float4*)(a + ln * 4);
    float4 a2 = *(const float4*)(a + 256 + ln * 4);
    float s_ = bf2f(hv.x) * a1.x + bf2f(hv.y) * a1.y + bf2f(hv.z) * a1.z + bf2f(hv.w) * a1.w;
    float t_ = bf2f(hv.x) * a2.x + bf2f(hv.y) * a2.y + bf2f(hv.z) * a2.z + bf2f(hv.w) * a2.w;
#pragma unroll
    for (int off = 32; off; off >>= 1) {
        s_ += __shfl_down(s_, off);
        t_ += __shfl_down(t_, off);
    }
    if (ln == 0) { s[j] = s_; t[j] = t_; }
}

// ---- k3b: wb / eL / eR; fill B1t aux rows (256 = ones, 257..271 = 0)
__global__ __launch_bounds__(256) void k_weights(const float* __restrict__ s,
                                                 const float* __restrict__ t,
                                                 float* __restrict__ wb,
                                                 float* __restrict__ eL,
                                                 float* __restrict__ eR,
                                                 unsigned short* __restrict__ B1t) {
    int j = blockIdx.x * 256 + threadIdx.x;
    float eb = s[(2 * j) & 8191] + t[(2 * j + 1) & 8191];
    eb = eb > 0.0f ? eb : 0.2f * eb;
    wb[j] = expf(eb);
    if (j < 4096) {
        float cL = s[2 * j] + t[2 * j];
        cL = cL > 0.0f ? cL : 0.2f * cL;
        float cR = s[2 * j + 1] + t[2 * j + 1];
        cR = cR > 0.0f ? cR : 0.2f * cR;
        eL[j] = expf(cL);
        eR[j] = expf(cR);
    }
    B1t[256 * 8192 + j] = 0x3F80;
#pragma unroll
    for (int f = 257; f < 272; f++) B1t[f * 8192 + j] = 0;
}

// ---- k4: B2t[f][j] = wb[j] * B1t[f][j]
__global__ __launch_bounds__(256) void k_b2(const unsigned short* __restrict__ B1t,
                                            const float* __restrict__ wb,
                                            unsigned short* __restrict__ B2t) {
    int j = blockIdx.x * 256 + threadIdx.x;
    int f = blockIdx.y;
    B2t[f * 8192 + j] = f2bf(wb[j] * bf2f(B1t[f * 8192 + j]));
}

// ---- k5: masked GEMM v9 (see header comment). BM=128 (4 waves x 32 rows),
// BN=272, BK=32, K=1024 per q-window. grid 512 = 2 blocks/CU.
__global__ __launch_bounds__(256, 2) void k_mgemm(const unsigned char* __restrict__ bits,
                                                  const unsigned short* __restrict__ B1t,
                                                  const unsigned short* __restrict__ B2t,
                                                  float* __restrict__ P) {
    __shared__ unsigned short Bsm[4 * 8704];   // 4 bufs x 17408 B, linear glds dest
    int tid = threadIdx.x, wv = tid >> 6, ln = tid & 63;
    int bid = blockIdx.x;
    int q = bid & 7;                 // XCD-pinned K-window
    int strip = bid >> 3;            // 0..63
    long K0 = (long)q * 1024;
    long m0 = (long)strip * 128;
    const unsigned short* Bt = (strip < 32) ? B1t : B2t;

    // B staging (v6/v7 proven): 1088 16B-chunks; 5 glds/wave (5th exec-masked
    // ln<16, still one VMEM inst). Global source pre-swizzled; read XOR'd.
    const unsigned short* sp[5];
    int cb[5];
#pragma unroll
    for (int i = 0; i < 4; i++) {
        int ch = i * 256 + wv * 64 + ln;
        int row = ch >> 2, c = ch & 3;
        cb[i] = (i * 256 + wv * 64) * 8;
        sp[i] = Bt + (long)row * 8192 + K0 + ((c ^ (row & 3)) << 3);
    }
    {
        int ch = 1024 + wv * 16 + (ln & 15);
        int row = ch >> 2, c = ch & 3;
        cb[4] = (1024 + wv * 16) * 8;
        sp[4] = Bt + (long)row * 8192 + K0 + ((c ^ (row & 3)) << 3);
    }

    // A bits: byte for step T = bits[row][q*128 + T*4 + (ln>>4)]
    const unsigned char* ap0 = bits + (m0 + wv * 32 + (ln & 15)) * 1024 + q * 128 + (ln >> 4);
    const unsigned char* ap1 = ap0 + 16 * 1024;

    f32x4 acc[2][17];
#pragma unroll
    for (int i = 0; i < 2; i++)
#pragma unroll
        for (int j = 0; j < 17; j++) acc[i][j] = (f32x4)0.0f;

    unsigned int ax0, ay0, ax1, ay1, ax2, ay2, ax3, ay3;   // 4 static A slots

#define STAGE_B(T, BUF) do {                                         \
        unsigned short* dst_ = Bsm + (BUF) * 8704;                   \
        long ko_ = (long)(T) * 32;                                   \
        glds16(sp[0] + ko_, dst_ + cb[0]);                           \
        glds16(sp[1] + ko_, dst_ + cb[1]);                           \
        glds16(sp[2] + ko_, dst_ + cb[2]);                           \
        glds16(sp[3] + ko_, dst_ + cb[3]);                           \
        if (ln < 16) glds16(sp[4] + ko_, dst_ + cb[4]);              \
    } while (0)

#define LOAD_AB(T, AX, AY) do {                                      \
        AX = ap0[(T) * 4];                                           \
        AY = ap1[(T) * 4];                                           \
    } while (0)

#define MSTEP(BUF, AX, AY) do {                                      \
        bf16x8 av0 = expand_byte(AX);                                \
        bf16x8 av1 = expand_byte(AY);                                \
        const char* base_ = (const char*)Bsm + (BUF) * 17408 + 64 * lr + swz16; \
        __builtin_amdgcn_s_setprio(1);                               \
        _Pragma("unroll")                                            \
        for (int f = 0; f < 17; f++) {                               \
            bf16x8 bv = *(const bf16x8*)(base_ + f * 1024);          \
            acc[0][f] = __builtin_amdgcn_mfma_f32_16x16x32_bf16(av0, bv, acc[0][f], 0, 0, 0); \
            acc[1][f] = __builtin_amdgcn_mfma_f32_16x16x32_bf16(av1, bv, acc[1][f], 0, 0, 0); \
        }                                                            \
        __builtin_amdgcn_s_setprio(0);                               \
    } while (0)

#define WB(N) do { asm volatile("s_waitcnt vmcnt(" #N ")" ::: "memory"); \
                   __builtin_amdgcn_s_barrier(); } while (0)

    int lr = ln & 15;
    int swz16 = 16 * ((ln >> 4) ^ (ln & 3));

    // prologue: A bytes (steps 0,1) FIRST, then B0..B2 -> vmcnt(10) drains
    // A+B0, keeps B1,B2 in flight.
    LOAD_AB(0, ax0, ay0);
    LOAD_AB(1, ax1, ay1);
    STAGE_B(0, 0);
    STAGE_B(1, 1);
    STAGE_B(2, 2);
    WB(10);

    // steps 0..3 peeled (vmcnt ramps 12 -> 14)
    LOAD_AB(2, ax2, ay2); STAGE_B(3, 3); MSTEP(0, ax0, ay0); WB(12);
    LOAD_AB(3, ax3, ay3); STAGE_B(4, 0); MSTEP(1, ax1, ay1); WB(14);
    LOAD_AB(4, ax0, ay0); STAGE_B(5, 1); MSTEP(2, ax2, ay2); WB(14);
    LOAD_AB(5, ax1, ay1); STAGE_B(6, 2); MSTEP(3, ax3, ay3); WB(14);

    // steady state: steps 4..27
#pragma unroll 1
    for (int t = 4; t < 28; t += 4) {
        LOAD_AB(t + 2, ax2, ay2); STAGE_B(t + 3, 3); MSTEP(0, ax0, ay0); WB(14);
        LOAD_AB(t + 3, ax3, ay3); STAGE_B(t + 4, 0); MSTEP(1, ax1, ay1); WB(14);
        LOAD_AB(t + 4, ax0, ay0); STAGE_B(t + 5, 1); MSTEP(2, ax2, ay2); WB(14);
        LOAD_AB(t + 5, ax1, ay1); STAGE_B(t + 6, 2); MSTEP(3, ax3, ay3); WB(14);
    }
    // tail: steps 28..31
    LOAD_AB(30, ax2, ay2); STAGE_B(31, 3); MSTEP(0, ax0, ay0); WB(14);
    LOAD_AB(31, ax3, ay3);                 MSTEP(1, ax1, ay1); WB(9);
    MSTEP(2, ax2, ay2);                                        WB(0);
    MSTEP(3, ax3, ay3);

#undef STAGE_B
#undef LOAD_AB
#undef MSTEP
#undef WB

    // epilogue: plain stores to this block's private q-partial (no atomics)
    long grow = m0 + wv * 32 + (ln >> 4) * 4;
    float* op = P + ((long)q * 8192 + grow) * 272 + lr;
#pragma unroll
    for (int mf = 0; mf < 2; mf++)
#pragma unroll
        for (int f = 0; f < 17; f++)
#pragma unroll
            for (int r = 0; r < 4; r++)
                op[(long)(mf * 16 + r) * 272 + f * 16] = acc[mf][f][r];
}

// ---- k6: combine 8 partials + elu
__global__ __launch_bounds__(256) void k_out(const float* __restrict__ P,
                                             const float* __restrict__ eL,
                                             const float* __restrict__ eR,
                                             float* __restrict__ outp) {
    int i = blockIdx.x, f = threadIdx.x;
    const float* p = P + (long)i * 272;
    const long QS = 8192l * 272;
    float num, den;
    if (i < 4096) {
        float tln = 0, trn = 0, tld = 0, trd = 0;
#pragma unroll
        for (int q = 0; q < 4; q++) { tln += p[q * QS + f]; tld += p[q * QS + 256]; }
#pragma unroll
        for (int q = 4; q < 8; q++) { trn += p[q * QS + f]; trd += p[q * QS + 256]; }
        float el = eL[i], er = eR[i];
        num = el * tln + er * trn;
        den = el * tld + er * trd;
    } else {
        num = 0; den = 0;
#pragma unroll
        for (int q = 0; q < 8; q++) { num += p[q * QS + f]; den += p[q * QS + 256]; }
    }
    float r = num / den;
    outp[(long)i * 256 + f] = r > 0.0f ? r : expm1f(r);
}

extern "C" void kernel_launch(void* const* d_in, const int* in_sizes, int n_in,
                              void* d_out, int out_size, void* d_ws, size_t ws_size,
                              hipStream_t stream) {
    (void)in_sizes; (void)n_in; (void)out_size; (void)ws_size;
    const float* x = (const float*)d_in[0];
    const int* sup = (const int*)d_in[1];
    const float* W = (const float*)d_in[2];
    const float* a = (const float*)d_in[3];
    float* outp = (float*)d_out;

    char* ws = (char*)d_ws;
    size_t off = 0;
    auto alloc = [&](size_t bytes) -> void* {
        void* p = ws + off;
        off += (bytes + 255) & ~(size_t)255;
        return p;
    };
    unsigned short* xb  = (unsigned short*)alloc(8192 * 512 * 2);
    unsigned short* Wbt = (unsigned short*)alloc(256 * 512 * 2);
    unsigned short* h   = (unsigned short*)alloc(8192 * 256 * 2);
    unsigned short* B1t = (unsigned short*)alloc(272 * 8192 * 2);
    unsigned short* B2t = (unsigned short*)alloc(272 * 8192 * 2);
    unsigned long long* bits = (unsigned long long*)alloc((size_t)8192 * 1024); // 8 MB
    float* s   = (float*)alloc(8192 * 4);
    float* t   = (float*)alloc(8192 * 4);
    float* wb  = (float*)alloc(8192 * 4);
    float* eL  = (float*)alloc(4096 * 4);
    float* eR  = (float*)alloc(4096 * 4);
    float* P   = (float*)alloc((size_t)8 * 8192 * 272 * 4);   // 71.3 MB partials

    k_pack<<<2048, 256, 0, stream>>>(sup, bits);
    k_cvt_x<<<4096, 256, 0, stream>>>(x, xb);
    k_cvt_w<<<512, 256, 0, stream>>>(W, Wbt);
    k_gemm_h<<<dim3(64, 4), 256, 0, stream>>>(xb, Wbt, h, B1t);
    k_st<<<2048, 256, 0, stream>>>(h, a, s, t);
    k_weights<<<32, 256, 0, stream>>>(s, t, wb, eL, eR, B1t);
    k_b2<<<dim3(32, 272), 256, 0, stream>>>(B1t, wb, B2t);
    k_mgemm<<<512, 256, 0, stream>>>((const unsigned char*)bits, B1t, B2t, P);
    k_out<<<8192, 256, 0, stream>>>(P, eL, eR, outp);
}